// Round 2
// baseline (339.419 us; speedup 1.0000x reference)
//
#include <hip/hip_runtime.h>
#include <hip/hip_bf16.h>
#include <math.h>

#define T_ 768
#define D_ 64
#define TD (T_*D_)
#define EPSF 1e-8f

__device__ __forceinline__ float wave_sum64(float v) {
#pragma unroll
  for (int m = 32; m >= 1; m >>= 1) v += __shfl_xor(v, m, 64);
  return v;
}
__device__ __forceinline__ float wave_max64(float v) {
#pragma unroll
  for (int m = 32; m >= 1; m >>= 1) v = fmaxf(v, __shfl_xor(v, m, 64));
  return v;
}
__device__ __forceinline__ float sigmoidf_(float x) { return 1.0f / (1.0f + expf(-x)); }

// temps[l] = sigmoid(dot(basin, temp_w[l]) + temp_b[l]) + 0.5
__global__ void temps_kernel(const float* __restrict__ basin,
                             const float* __restrict__ temp_w,
                             const float* __restrict__ temp_b,
                             float* __restrict__ temps) {
  int wave = threadIdx.x >> 6, lane = threadIdx.x & 63;
  float v = basin[lane] * temp_w[wave * 64 + lane];
  v = wave_sum64(v);
  if (lane == 0) temps[wave] = sigmoidf_(v + temp_b[wave]) + 0.5f;
}

// From x row compute p (simplex proj + renorm) and feature row
// f = [sqrt(p), sqrt(eps/2)/sqrt(p)]  (128 floats). 4 rows per block.
__device__ __forceinline__ void feat_from_x(float v, int t, int d, float* __restrict__ F) {
  float sp = fmaxf(v, 0.0f) + log1pf(expf(-fabsf(v)));
  float s = wave_sum64(sp);
  float p1 = sp / (s + EPSF);
  p1 = fmaxf(p1, EPSF);
  float s2 = wave_sum64(p1);
  float p = p1 / (s2 + EPSF);
  F[t * 128 + d] = sqrtf(p);
  F[t * 128 + 64 + d] = sqrtf(5e-9f / p);
}

__global__ void __launch_bounds__(256)
feat_kernel(const float* __restrict__ x, float* __restrict__ F) {
  int t = blockIdx.x * 4 + (threadIdx.x >> 6);
  int d = threadIdx.x & 63;
  feat_from_x(x[t * 64 + d], t, d, F);
}

// pass-1 fused: x' = x*g + prev*(1-g), write x' and features of x'
__global__ void __launch_bounds__(256)
gatefeat_kernel(const float* __restrict__ x_in, const float* __restrict__ prev,
                const float* __restrict__ W, const float* __restrict__ b,
                float* __restrict__ x_out, float* __restrict__ F) {
  __shared__ float xs[4][64], ps[4][64];
  int w = threadIdx.x >> 6, d = threadIdx.x & 63;
  int t = blockIdx.x * 4 + w;
  xs[w][d] = x_in[t * 64 + d];
  ps[w][d] = prev[t * 64 + d];
  __syncthreads();
  const float4* w4 = reinterpret_cast<const float4*>(W + d * 128);
  float acc = b[d];
#pragma unroll
  for (int q = 0; q < 16; q++) {
    float4 c = w4[q];
    acc += xs[w][q * 4 + 0] * c.x + xs[w][q * 4 + 1] * c.y +
           xs[w][q * 4 + 2] * c.z + xs[w][q * 4 + 3] * c.w;
  }
#pragma unroll
  for (int q = 0; q < 16; q++) {
    float4 c = w4[16 + q];
    acc += ps[w][q * 4 + 0] * c.x + ps[w][q * 4 + 1] * c.y +
           ps[w][q * 4 + 2] * c.z + ps[w][q * 4 + 3] * c.w;
  }
  float g = sigmoidf_(acc);
  float xv = xs[w][d] * g + ps[w][d] * (1.0f - g);
  x_out[t * 64 + d] = xv;
  feat_from_x(xv, t, d, F);
}

// Gram GEMM: LW[i][j] = -2*acos(clamp(dot(F_i,F_j))) / temp
// tile 32(i) x 64(j), BK=32, 256 threads, micro 2x4
__global__ void __launch_bounds__(256)
gram_kernel(const float* __restrict__ F, const float* __restrict__ temps, int layer,
            float* __restrict__ LW) {
  __shared__ float As[32][34];
  __shared__ float Bs[32][64];
  int i0 = blockIdx.y * 32, j0 = blockIdx.x * 64;
  int tid = threadIdx.x;
  int ty = tid >> 4, tx = tid & 15;
  float acc[2][4];
#pragma unroll
  for (int m = 0; m < 2; m++)
#pragma unroll
    for (int n = 0; n < 4; n++) acc[m][n] = 0.0f;

  const float4* F4 = reinterpret_cast<const float4*>(F);
  int li = tid >> 3, lk = tid & 7;
  for (int kt = 0; kt < 4; kt++) {
    float4 a4 = F4[(i0 + li) * 32 + kt * 8 + lk];
    As[lk * 4 + 0][li] = a4.x; As[lk * 4 + 1][li] = a4.y;
    As[lk * 4 + 2][li] = a4.z; As[lk * 4 + 3][li] = a4.w;
#pragma unroll
    for (int rep = 0; rep < 2; rep++) {
      int j = li + rep * 32;
      float4 b4 = F4[(j0 + j) * 32 + kt * 8 + lk];
      Bs[lk * 4 + 0][j] = b4.x; Bs[lk * 4 + 1][j] = b4.y;
      Bs[lk * 4 + 2][j] = b4.z; Bs[lk * 4 + 3][j] = b4.w;
    }
    __syncthreads();
#pragma unroll
    for (int k = 0; k < 32; k++) {
      float2 a = *reinterpret_cast<const float2*>(&As[k][ty * 2]);
      float4 b = *reinterpret_cast<const float4*>(&Bs[k][tx * 4]);
      acc[0][0] += a.x * b.x; acc[0][1] += a.x * b.y;
      acc[0][2] += a.x * b.z; acc[0][3] += a.x * b.w;
      acc[1][0] += a.y * b.x; acc[1][1] += a.y * b.y;
      acc[1][2] += a.y * b.z; acc[1][3] += a.y * b.w;
    }
    __syncthreads();
  }
  float inv_t = 1.0f / fmaxf(temps[layer], 1e-6f);
#pragma unroll
  for (int m = 0; m < 2; m++) {
    int row = i0 + ty * 2 + m;
    float4 o;
    float* po = &o.x;
#pragma unroll
    for (int n = 0; n < 4; n++) {
      float inner = fminf(fmaxf(acc[m][n], -1.0f + 1e-6f), 1.0f - 1e-6f);
      po[n] = -2.0f * acosf(inner) * inv_t;
    }
    *reinterpret_cast<float4*>(&LW[row * 768 + j0 + tx * 4]) = o;
  }
}

// fused row-softmax + PV GEMM + residual. 16 rows per block, 48 blocks.
__global__ void __launch_bounds__(256)
pvsm_kernel(const float* __restrict__ LW, const float* __restrict__ x,
            const float* __restrict__ rs_layers, int layer,
            float* __restrict__ x_out) {
  __shared__ float wt[16][68];
  __shared__ float xs[64][64];
  __shared__ float mx[16], isum[16];
  int i0 = blockIdx.x * 16;
  int tid = threadIdx.x;
  int wave = tid >> 6, lane = tid & 63;

  // phase A: per-row max & expsum (wave per 4 rows)
  for (int rr = 0; rr < 4; rr++) {
    int row = wave * 4 + rr;
    float vals[12];
    float m = -1e30f;
#pragma unroll
    for (int q = 0; q < 12; q++) {
      vals[q] = LW[(i0 + row) * 768 + q * 64 + lane];
      m = fmaxf(m, vals[q]);
    }
    m = wave_max64(m);
    float s = 0.0f;
#pragma unroll
    for (int q = 0; q < 12; q++) s += expf(vals[q] - m);
    s = wave_sum64(s);
    if (lane == 0) { mx[row] = m; isum[row] = 1.0f / s; }
  }
  __syncthreads();

  // phase B: PV with exp applied at staging
  int ty = tid >> 4, tx = tid & 15;   // row ty (0..15), cols tx*4..+3
  float4 acc = make_float4(0.f, 0.f, 0.f, 0.f);
  const float4* x4 = reinterpret_cast<const float4*>(x);
  float4* xs4 = reinterpret_cast<float4*>(&xs[0][0]);
  for (int jt = 0; jt < 12; jt++) {
    // stage weights: 16x64, one float4 per thread
    {
      const float4 raw = *reinterpret_cast<const float4*>(
          &LW[(i0 + ty) * 768 + jt * 64 + tx * 4]);
      float m = mx[ty], is = isum[ty];
      wt[ty][tx * 4 + 0] = expf(raw.x - m) * is;
      wt[ty][tx * 4 + 1] = expf(raw.y - m) * is;
      wt[ty][tx * 4 + 2] = expf(raw.z - m) * is;
      wt[ty][tx * 4 + 3] = expf(raw.w - m) * is;
    }
    // stage x tile 64x64: 4 float4 per thread
#pragma unroll
    for (int rep = 0; rep < 4; rep++) {
      int idx = tid + rep * 256;      // 0..1023
      int j = idx >> 4, c4 = idx & 15;
      xs4[j * 16 + c4] = x4[(jt * 64 + j) * 16 + c4];
    }
    __syncthreads();
#pragma unroll 16
    for (int j = 0; j < 64; j++) {
      float w = wt[ty][j];
      float4 xv = xs4[j * 16 + tx];
      acc.x += w * xv.x; acc.y += w * xv.y;
      acc.z += w * xv.z; acc.w += w * xv.w;
    }
    __syncthreads();
  }
  float rs = rs_layers[layer];
  int row = i0 + ty;
  float4 xi = x4[row * 16 + tx];
  float4 o;
  o.x = xi.x + rs * (acc.x - xi.x);
  o.y = xi.y + rs * (acc.y - xi.y);
  o.z = xi.z + rs * (acc.z - xi.z);
  o.w = xi.w + rs * (acc.w - xi.w);
  reinterpret_cast<float4*>(x_out)[row * 16 + tx] = o;
}

// parallel pooling: block b sums rows 64b..64b+63 -> pool_part[b][64]
__global__ void __launch_bounds__(256)
pool_kernel(const float* __restrict__ x, float* __restrict__ pool_part) {
  __shared__ float part[4][64];
  int wave = threadIdx.x >> 6, lane = threadIdx.x & 63;
  float acc = 0.0f;
  int base = blockIdx.x * 64 + wave * 16;
  for (int rr = 0; rr < 16; rr++) acc += x[(base + rr) * 64 + lane];
  part[wave][lane] = acc;
  __syncthreads();
  if (threadIdx.x < 64)
    pool_part[blockIdx.x * 64 + threadIdx.x] =
        part[0][threadIdx.x] + part[1][threadIdx.x] +
        part[2][threadIdx.x] + part[3][threadIdx.x];
}

__global__ void mlp_kernel(const float* __restrict__ pool_part, float* __restrict__ basin,
                           const float* __restrict__ w1, const float* __restrict__ b1,
                           const float* __restrict__ w2, const float* __restrict__ b2,
                           const float* __restrict__ uw, const float* __restrict__ ub) {
  __shared__ float pooled[64], h1[32], agg[64], bs[64];
  int tid = threadIdx.x;
  if (tid < 64) {
    float s = 0.0f;
    for (int b = 0; b < 12; b++) s += pool_part[b * 64 + tid];
    pooled[tid] = s * (1.0f / T_);
    bs[tid] = basin[tid];
  }
  __syncthreads();
  if (tid < 32) {
    float a = b1[tid];
    for (int k = 0; k < 64; k++) a += w1[tid * 64 + k] * pooled[k];
    h1[tid] = tanhf(a);
  }
  __syncthreads();
  if (tid < 64) {
    float a = b2[tid];
    for (int k = 0; k < 32; k++) a += w2[tid * 32 + k] * h1[k];
    agg[tid] = tanhf(a);
  }
  __syncthreads();
  if (tid < 64) {
    float a = ub[tid];
    for (int k = 0; k < 64; k++) a += uw[tid * 128 + k] * bs[k];
    for (int k = 0; k < 64; k++) a += uw[tid * 128 + 64 + k] * agg[k];
    float g = sigmoidf_(a);
    basin[tid] = bs[tid] * (1.0f - g) + agg[tid] * g;
  }
}

__global__ void final_kernel(const float* __restrict__ x, const float* __restrict__ basin_seq,
                             const float* __restrict__ res_scale, float* __restrict__ out) {
  int idx = blockIdx.x * blockDim.x + threadIdx.x;
  if (idx < TD) {
    float xv = x[idx];
    out[idx] = xv + 0.01f * res_scale[0] * (xv - basin_seq[idx]);
  }
}

extern "C" void kernel_launch(void* const* d_in, const int* in_sizes, int n_in,
                              void* d_out, int out_size, void* d_ws, size_t ws_size,
                              hipStream_t stream) {
  const float* basin_seq    = (const float*)d_in[0];
  const float* basin_coords = (const float*)d_in[1];
  const float* temp_w       = (const float*)d_in[2];
  const float* temp_b       = (const float*)d_in[3];
  const float* rs_layers    = (const float*)d_in[4];
  const float* fb_w         = (const float*)d_in[5];   // (4,64,128)
  const float* fb_b         = (const float*)d_in[6];   // (4,64)
  const float* comp_w1      = (const float*)d_in[7];
  const float* comp_b1      = (const float*)d_in[8];
  const float* comp_w2      = (const float*)d_in[9];
  const float* comp_b2      = (const float*)d_in[10];
  const float* upd_w        = (const float*)d_in[11];
  const float* upd_b        = (const float*)d_in[12];
  const float* res_scale    = (const float*)d_in[13];
  float* out = (float*)d_out;

  float* ws = (float*)d_ws;
  float* LW   = ws;                       // 768*768
  float* F    = LW + 768 * 768;           // 768*128
  float* prev[4];
  for (int l = 0; l < 4; l++) prev[l] = F + 768 * 128 + l * TD;
  float* bufA = prev[3] + TD;
  float* bufB = bufA + TD;
  float* pool_part = bufB + TD;           // 12*64
  float* basin = pool_part + 12 * 64;     // 64
  float* temps = basin + 64;              // 4

  hipMemcpyAsync(bufA, basin_seq, TD * sizeof(float), hipMemcpyDeviceToDevice, stream);
  hipMemcpyAsync(basin, basin_coords, 64 * sizeof(float), hipMemcpyDeviceToDevice, stream);

  dim3 gram_grid(12, 24);

  // ---- pass 0 ----
  temps_kernel<<<1, 256, 0, stream>>>(basin, temp_w, temp_b, temps);
  const float* x = bufA;
  for (int l = 0; l < 4; l++) {
    feat_kernel<<<192, 256, 0, stream>>>(x, F);
    gram_kernel<<<gram_grid, 256, 0, stream>>>(F, temps, l, LW);
    pvsm_kernel<<<48, 256, 0, stream>>>(LW, x, rs_layers, l, prev[l]);
    x = prev[l];
  }
  pool_kernel<<<12, 256, 0, stream>>>(x, pool_part);
  mlp_kernel<<<1, 256, 0, stream>>>(pool_part, basin, comp_w1, comp_b1,
                                    comp_w2, comp_b2, upd_w, upd_b);

  // ---- pass 1 ----
  temps_kernel<<<1, 256, 0, stream>>>(basin, temp_w, temp_b, temps);
  for (int l = 0; l < 4; l++) {
    float* xg = (l & 1) ? bufB : bufA;      // gate output
    float* xo = (l & 1) ? bufA : bufB;      // attn output
    gatefeat_kernel<<<192, 256, 0, stream>>>(x, prev[l], fb_w + l * 64 * 128,
                                             fb_b + l * 64, xg, F);
    gram_kernel<<<gram_grid, 256, 0, stream>>>(F, temps, l, LW);
    pvsm_kernel<<<48, 256, 0, stream>>>(LW, xg, rs_layers, l, xo);
    x = xo;
  }

  final_kernel<<<(TD + 255) / 256, 256, 0, stream>>>(x, basin_seq, res_scale, out);
}

// Round 3
// 184.483 us; speedup vs baseline: 1.8398x; 1.8398x over previous
//
#include <hip/hip_runtime.h>
#include <math.h>

#define T_ 768
#define D_ 64
#define TD (T_*D_)
#define EPSF 1e-8f

__device__ __forceinline__ float wave_sum64(float v) {
#pragma unroll
  for (int m = 32; m >= 1; m >>= 1) v += __shfl_xor(v, m, 64);
  return v;
}
__device__ __forceinline__ float wave_max64(float v) {
#pragma unroll
  for (int m = 32; m >= 1; m >>= 1) v = fmaxf(v, __shfl_xor(v, m, 64));
  return v;
}
__device__ __forceinline__ float sigmoidf_(float x) { return 1.0f / (1.0f + expf(-x)); }

// simplex projection + renorm + feature split:
// f = [sqrt(p), sqrt(eps/2)/sqrt(p)]  so dot(f_i,f_j) ~= sum sqrt(p_i p_j + eps)
__device__ __forceinline__ void feat_store(float v, int row, int lane,
                                           float* __restrict__ F, float* __restrict__ FT) {
  float sp = fmaxf(v, 0.0f) + log1pf(expf(-fabsf(v)));
  float s = wave_sum64(sp);
  float p1 = fmaxf(sp / (s + EPSF), EPSF);
  float s2 = wave_sum64(p1);
  float p = p1 / (s2 + EPSF);
  float f1 = sqrtf(p);
  float f2 = sqrtf(5e-9f / p);
  F[row * 128 + lane] = f1;
  F[row * 128 + 64 + lane] = f2;
  FT[lane * 768 + row] = f1;
  FT[(64 + lane) * 768 + row] = f2;
}

// features(basin_seq) + fb_w transpose + pass-0 temps
__global__ void __launch_bounds__(256)
phaseA_kernel(const float* __restrict__ bseq, const float* __restrict__ basin_coords,
              const float* __restrict__ temp_w, const float* __restrict__ temp_b,
              const float* __restrict__ fb_w,
              float* __restrict__ F, float* __restrict__ FT,
              float* __restrict__ fbwT, float* __restrict__ temps) {
  int b = blockIdx.x, tid = threadIdx.x;
  int w = tid >> 6, lane = tid & 63;
  if (w < 3) {
    int row = b * 3 + w;
    feat_store(bseq[row * 64 + lane], row, lane, F, FT);
  }
  if (tid < 128) {              // transpose fb_w: 4*64*128 elems over 256 blocks
    int idx = b * 128 + tid;
    int l = idx >> 13, r = idx & 8191;
    int d = r >> 7, k = r & 127;
    fbwT[l * 8192 + k * 64 + d] = fb_w[l * 8192 + d * 128 + k];
  }
  if (b == 0 && w < 4) {
    float v = basin_coords[lane] * temp_w[w * 64 + lane];
    v = wave_sum64(v);
    if (lane == 0) temps[w] = sigmoidf_(v + temp_b[w]) + 0.5f;
  }
}

// Fully fused layer: Gram->acos->softmax->PV->residual->(prev store | gate tail | pool | final)
__global__ void __launch_bounds__(256)
layer_kernel(const float* __restrict__ xin, float* __restrict__ xout,
             const float* __restrict__ Fin, const float* __restrict__ FTin,
             float* __restrict__ Fw, float* __restrict__ FTw,
             const float* __restrict__ temps, int toff, int lidx,
             const float* __restrict__ rs_layers,
             float* __restrict__ prevW,
             const float* __restrict__ WTnext, const float* __restrict__ bnext,
             const float* __restrict__ prevNext,
             float* __restrict__ poolPart,
             const float* __restrict__ bseq, const float* __restrict__ res_scale,
             float* __restrict__ finalOut,
             int doFeat) {
  __shared__ float As4[128][4];
  __shared__ float logits[3][768];
  __shared__ float probs4[768][4];
  __shared__ float pvpart[16 * 3 * 16 * 4];
  __shared__ float xs[3][64], ps[3][64];
  int b = blockIdx.x, tid = threadIdx.x;
  int w = tid >> 6, lane = tid & 63;
  int i0 = b * 3;

  if (tid < 128) {
    As4[tid][0] = Fin[(i0 + 0) * 128 + tid];
    As4[tid][1] = Fin[(i0 + 1) * 128 + tid];
    As4[tid][2] = Fin[(i0 + 2) * 128 + tid];
    As4[tid][3] = 0.0f;
  }
  __syncthreads();

  // ---- QK: 3 rows x 768 cols, K=128; thread = one j-quad ----
  if (tid < 192) {
    int jq = tid;
    const float4* FT4 = reinterpret_cast<const float4*>(FTin);
    float acc[3][4];
#pragma unroll
    for (int i = 0; i < 3; i++)
#pragma unroll
      for (int c = 0; c < 4; c++) acc[i][c] = 0.0f;
#pragma unroll 4
    for (int k = 0; k < 128; k++) {
      float4 bv = FT4[k * 192 + jq];          // coalesced global (L2)
      float4 av = *reinterpret_cast<const float4*>(&As4[k][0]);  // LDS broadcast
      const float* bp = &bv.x;
      const float* ap = &av.x;
#pragma unroll
      for (int i = 0; i < 3; i++)
#pragma unroll
        for (int c = 0; c < 4; c++) acc[i][c] += ap[i] * bp[c];
    }
    float inv_t = 1.0f / fmaxf(temps[toff + lidx], 1e-6f);
#pragma unroll
    for (int i = 0; i < 3; i++) {
      float4 o;
      float* op = &o.x;
#pragma unroll
      for (int c = 0; c < 4; c++) {
        float inner = fminf(fmaxf(acc[i][c], -1.0f + 1e-6f), 1.0f - 1e-6f);
        op[c] = -2.0f * acosf(inner) * inv_t;
      }
      *reinterpret_cast<float4*>(&logits[i][jq * 4]) = o;
    }
  }
  __syncthreads();

  // ---- softmax: wave w handles row w ----
  if (w < 3) {
    float vals[12];
    float m = -1e30f;
#pragma unroll
    for (int q = 0; q < 12; q++) {
      vals[q] = logits[w][q * 64 + lane];
      m = fmaxf(m, vals[q]);
    }
    m = wave_max64(m);
    float s = 0.0f;
#pragma unroll
    for (int q = 0; q < 12; q++) { vals[q] = expf(vals[q] - m); s += vals[q]; }
    s = wave_sum64(s);
    float is = 1.0f / s;
#pragma unroll
    for (int q = 0; q < 12; q++) probs4[q * 64 + lane][w] = vals[q] * is;
  }
  __syncthreads();

  // ---- PV: thread (dq, jg): 48 j's, all 3 rows, 4 cols ----
  {
    int dq = tid & 15, jg = tid >> 4;
    float acc[3][4];
#pragma unroll
    for (int i = 0; i < 3; i++)
#pragma unroll
      for (int c = 0; c < 4; c++) acc[i][c] = 0.0f;
    const float4* xin4 = reinterpret_cast<const float4*>(xin);
    for (int q = 0; q < 48; q++) {
      int j = jg * 48 + q;
      float4 pr = *reinterpret_cast<const float4*>(&probs4[j][0]);
      float4 xv = xin4[j * 16 + dq];
      const float* pp = &pr.x;
      const float* xp = &xv.x;
#pragma unroll
      for (int i = 0; i < 3; i++)
#pragma unroll
        for (int c = 0; c < 4; c++) acc[i][c] += pp[i] * xp[c];
    }
#pragma unroll
    for (int i = 0; i < 3; i++) {
      float4 o = make_float4(acc[i][0], acc[i][1], acc[i][2], acc[i][3]);
      *reinterpret_cast<float4*>(&pvpart[((jg * 3 + i) * 16 + dq) * 4]) = o;
    }
  }
  __syncthreads();

  // ---- combine + residual + tails ----
  float xo = 0.0f;
  int row = i0 + w;
  if (w < 3) {
    float s = 0.0f;
#pragma unroll
    for (int jg = 0; jg < 16; jg++) s += pvpart[jg * 192 + w * 64 + lane];
    float xi = xin[row * 64 + lane];
    float rs = rs_layers[lidx];
    xo = xi + rs * (s - xi);
    if (prevW) prevW[row * 64 + lane] = xo;
    if (finalOut) {
      finalOut[row * 64 + lane] = xo + 0.01f * res_scale[0] * (xo - bseq[row * 64 + lane]);
    } else if (WTnext) {
      xs[w][lane] = xo;
      ps[w][lane] = prevNext[row * 64 + lane];
    } else {
      xout[row * 64 + lane] = xo;
      if (doFeat) feat_store(xo, row, lane, Fw, FTw);
      if (poolPart) xs[w][lane] = xo;
    }
  }
  __syncthreads();
  if (WTnext && !finalOut && w < 3) {     // feedback gate for NEXT ref-layer
    float a = bnext[lane];
#pragma unroll 8
    for (int k = 0; k < 64; k++) a += xs[w][k] * WTnext[k * 64 + lane];
#pragma unroll 8
    for (int k = 0; k < 64; k++) a += ps[w][k] * WTnext[(64 + k) * 64 + lane];
    float g = sigmoidf_(a);
    float xn = xo * g + ps[w][lane] * (1.0f - g);
    xout[row * 64 + lane] = xn;
    feat_store(xn, row, lane, Fw, FTw);
  }
  if (poolPart && tid < 64)
    poolPart[b * 64 + tid] = xs[0][tid] + xs[1][tid] + xs[2][tid];
}

// gate(pass1 layer0) on all blocks; block 0 also: pool-reduce -> MLP -> basin -> temps(pass1)
__global__ void __launch_bounds__(256)
compress_kernel(const float* __restrict__ xin, float* __restrict__ xout,
                const float* __restrict__ prev0,
                const float* __restrict__ WT0, const float* __restrict__ b0,
                float* __restrict__ Fw, float* __restrict__ FTw,
                const float* __restrict__ part,
                const float* __restrict__ basin_coords,
                const float* __restrict__ temp_w, const float* __restrict__ temp_b,
                const float* __restrict__ w1, const float* __restrict__ b1,
                const float* __restrict__ w2, const float* __restrict__ b2,
                const float* __restrict__ uw, const float* __restrict__ ub,
                float* __restrict__ temps) {
  __shared__ float xs[3][64], ps[3][64];
  __shared__ float cpart[4][64];
  __shared__ float pooled[64], h1s[32], aggs[64], bnew[64];
  int b = blockIdx.x, tid = threadIdx.x;
  int w = tid >> 6, lane = tid & 63;
  int i0 = b * 3;
  if (w < 3) {
    int row = i0 + w;
    xs[w][lane] = xin[row * 64 + lane];
    ps[w][lane] = prev0[row * 64 + lane];
  }
  __syncthreads();
  if (w < 3) {
    int row = i0 + w;
    float a = b0[lane];
#pragma unroll 8
    for (int k = 0; k < 64; k++) a += xs[w][k] * WT0[k * 64 + lane];
#pragma unroll 8
    for (int k = 0; k < 64; k++) a += ps[w][k] * WT0[(64 + k) * 64 + lane];
    float g = sigmoidf_(a);
    float xn = xs[w][lane] * g + ps[w][lane] * (1.0f - g);
    xout[row * 64 + lane] = xn;
    feat_store(xn, row, lane, Fw, FTw);
  }
  if (b == 0) {
    {
      float s = 0.0f;
      for (int r = 0; r < 64; r++) s += part[(w * 64 + r) * 64 + lane];
      cpart[w][lane] = s;
    }
    __syncthreads();
    if (tid < 64)
      pooled[tid] = (cpart[0][tid] + cpart[1][tid] + cpart[2][tid] + cpart[3][tid]) *
                    (1.0f / 768.0f);
    __syncthreads();
    if (tid < 32) {
      float a = b1[tid];
      for (int k = 0; k < 64; k++) a += w1[tid * 64 + k] * pooled[k];
      h1s[tid] = tanhf(a);
    }
    __syncthreads();
    if (tid < 64) {
      float a = b2[tid];
      for (int k = 0; k < 32; k++) a += w2[tid * 32 + k] * h1s[k];
      aggs[tid] = tanhf(a);
    }
    __syncthreads();
    if (tid < 64) {
      float a = ub[tid];
      for (int k = 0; k < 64; k++) a += uw[tid * 128 + k] * basin_coords[k];
      for (int k = 0; k < 64; k++) a += uw[tid * 128 + 64 + k] * aggs[k];
      float g = sigmoidf_(a);
      bnew[tid] = basin_coords[tid] * (1.0f - g) + aggs[tid] * g;
    }
    __syncthreads();
    if (w < 4) {
      float v = bnew[lane] * temp_w[w * 64 + lane];
      v = wave_sum64(v);
      if (lane == 0) temps[4 + w] = sigmoidf_(v + temp_b[w]) + 0.5f;
    }
  }
}

extern "C" void kernel_launch(void* const* d_in, const int* in_sizes, int n_in,
                              void* d_out, int out_size, void* d_ws, size_t ws_size,
                              hipStream_t stream) {
  const float* bseq         = (const float*)d_in[0];
  const float* basin_coords = (const float*)d_in[1];
  const float* temp_w       = (const float*)d_in[2];
  const float* temp_b       = (const float*)d_in[3];
  const float* rs_layers    = (const float*)d_in[4];
  const float* fb_w         = (const float*)d_in[5];
  const float* fb_b         = (const float*)d_in[6];
  const float* comp_w1      = (const float*)d_in[7];
  const float* comp_b1      = (const float*)d_in[8];
  const float* comp_w2      = (const float*)d_in[9];
  const float* comp_b2      = (const float*)d_in[10];
  const float* upd_w        = (const float*)d_in[11];
  const float* upd_b        = (const float*)d_in[12];
  const float* res_scale    = (const float*)d_in[13];
  float* out = (float*)d_out;

  float* ws = (float*)d_ws;
  float* F0    = ws;                  // 768*128
  float* FT0   = F0 + 98304;          // 128*768
  float* F1    = FT0 + 98304;
  float* FT1   = F1 + 98304;
  float* xA    = FT1 + 98304;         // 768*64
  float* xB    = xA + TD;
  float* prevb = xB + TD;             // 4*768*64
  float* fbwT  = prevb + 4 * TD;      // 4*128*64
  float* part  = fbwT + 32768;        // 256*64
  float* temps = part + 16384;        // 8

  phaseA_kernel<<<256, 256, 0, stream>>>(bseq, basin_coords, temp_w, temp_b, fb_w,
                                         F0, FT0, fbwT, temps);
  // ---- pass 0 ----
  layer_kernel<<<256, 256, 0, stream>>>(bseq, xA, F0, FT0, F1, FT1, temps, 0, 0, rs_layers,
                                        prevb + 0 * TD, nullptr, nullptr, nullptr,
                                        nullptr, nullptr, nullptr, nullptr, 1);
  layer_kernel<<<256, 256, 0, stream>>>(xA, xB, F1, FT1, F0, FT0, temps, 0, 1, rs_layers,
                                        prevb + 1 * TD, nullptr, nullptr, nullptr,
                                        nullptr, nullptr, nullptr, nullptr, 1);
  layer_kernel<<<256, 256, 0, stream>>>(xB, xA, F0, FT0, F1, FT1, temps, 0, 2, rs_layers,
                                        prevb + 2 * TD, nullptr, nullptr, nullptr,
                                        nullptr, nullptr, nullptr, nullptr, 1);
  layer_kernel<<<256, 256, 0, stream>>>(xA, xB, F1, FT1, nullptr, nullptr, temps, 0, 3,
                                        rs_layers, prevb + 3 * TD, nullptr, nullptr, nullptr,
                                        part, nullptr, nullptr, nullptr, 0);
  // ---- compress + gate(pass1,l=0) ----
  compress_kernel<<<256, 256, 0, stream>>>(xB, xA, prevb + 0 * TD, fbwT + 0 * 8192,
                                           fb_b + 0 * 64, F0, FT0, part, basin_coords,
                                           temp_w, temp_b, comp_w1, comp_b1, comp_w2,
                                           comp_b2, upd_w, upd_b, temps);
  // ---- pass 1 ----
  layer_kernel<<<256, 256, 0, stream>>>(xA, xB, F0, FT0, F1, FT1, temps, 4, 0, rs_layers,
                                        nullptr, fbwT + 1 * 8192, fb_b + 1 * 64,
                                        prevb + 1 * TD, nullptr, nullptr, nullptr, nullptr, 0);
  layer_kernel<<<256, 256, 0, stream>>>(xB, xA, F1, FT1, F0, FT0, temps, 4, 1, rs_layers,
                                        nullptr, fbwT + 2 * 8192, fb_b + 2 * 64,
                                        prevb + 2 * TD, nullptr, nullptr, nullptr, nullptr, 0);
  layer_kernel<<<256, 256, 0, stream>>>(xA, xB, F0, FT0, F1, FT1, temps, 4, 2, rs_layers,
                                        nullptr, fbwT + 3 * 8192, fb_b + 3 * 64,
                                        prevb + 3 * TD, nullptr, nullptr, nullptr, nullptr, 0);
  layer_kernel<<<256, 256, 0, stream>>>(xB, nullptr, F1, FT1, nullptr, nullptr, temps, 4, 3,
                                        rs_layers, nullptr, nullptr, nullptr, nullptr,
                                        nullptr, bseq, res_scale, out, 0);
}